// Round 4
// baseline (137.302 us; speedup 1.0000x reference)
//
#include <hip/hip_runtime.h>

#define THRESH 1.0f

typedef float fvec4 __attribute__((ext_vector_type(4)));

// ---------- W transpose: Wt[k][m] = W[m][k] (into d_ws) ----------
__global__ __launch_bounds__(256) void transpose_kernel(
    const float* __restrict__ W, float* __restrict__ Wt, int M, int D)
{
    __shared__ float tile[32][33];
    const int tilesK = D / 32;
    const int bx = blockIdx.x % tilesK;   // k tile
    const int by = blockIdx.x / tilesK;   // m tile
    const int lx = threadIdx.x & 31;
    const int ly = threadIdx.x >> 5;      // 0..7
    #pragma unroll
    for (int j = 0; j < 4; ++j)
        tile[ly + j * 8][lx] = W[(size_t)(by * 32 + ly + j * 8) * D + bx * 32 + lx];
    __syncthreads();
    #pragma unroll
    for (int j = 0; j < 4; ++j)
        Wt[(size_t)(bx * 32 + ly + j * 8) * M + by * 32 + lx] = tile[lx][ly + j * 8];
}

// ---------- scores = softmax(x @ W^T + b); 4 batch rows per block ----------
// Thread tid owns logit m=tid for 4 rows; Wt loads reused x4.
__global__ __launch_bounds__(256) void scores_kernel4(
    const float* __restrict__ Wt, const float* __restrict__ x,
    const float* __restrict__ bias, float* __restrict__ scores,
    int D, int M)
{
    const int b0   = blockIdx.x * 4;
    const int tid  = threadIdx.x;
    const int wave = tid >> 6;
    const int lane = tid & 63;
    __shared__ __align__(16) float x_lds[4][256];
    __shared__ float wredm[4][4];   // [row][wave]
    __shared__ float wreds[4][4];

    #pragma unroll
    for (int r = 0; r < 4; ++r)
        x_lds[r][tid] = x[(size_t)(b0 + r) * D + tid];
    __syncthreads();

    float a0 = 0.f, a1 = 0.f, a2 = 0.f, a3 = 0.f;
    #pragma unroll 2
    for (int k4 = 0; k4 < D / 4; ++k4) {
        const fvec4 x0 = reinterpret_cast<const fvec4*>(x_lds[0])[k4];
        const fvec4 x1 = reinterpret_cast<const fvec4*>(x_lds[1])[k4];
        const fvec4 x2 = reinterpret_cast<const fvec4*>(x_lds[2])[k4];
        const fvec4 x3 = reinterpret_cast<const fvec4*>(x_lds[3])[k4];
        #pragma unroll
        for (int j = 0; j < 4; ++j) {
            const float w = Wt[(size_t)(k4 * 4 + j) * M + tid];
            a0 = fmaf(w, x0[j], a0);
            a1 = fmaf(w, x1[j], a1);
            a2 = fmaf(w, x2[j], a2);
            a3 = fmaf(w, x3[j], a3);
        }
    }
    const float bv = bias[tid];
    float l0 = a0 + bv, l1 = a1 + bv, l2 = a2 + bv, l3 = a3 + bv;

    // per-row block max (4 independent butterfly chains for ILP)
    float m0 = l0, m1 = l1, m2 = l2, m3 = l3;
    #pragma unroll
    for (int off = 32; off; off >>= 1) {
        m0 = fmaxf(m0, __shfl_xor(m0, off, 64));
        m1 = fmaxf(m1, __shfl_xor(m1, off, 64));
        m2 = fmaxf(m2, __shfl_xor(m2, off, 64));
        m3 = fmaxf(m3, __shfl_xor(m3, off, 64));
    }
    if (lane == 0) {
        wredm[0][wave] = m0; wredm[1][wave] = m1;
        wredm[2][wave] = m2; wredm[3][wave] = m3;
    }
    __syncthreads();
    m0 = fmaxf(fmaxf(wredm[0][0], wredm[0][1]), fmaxf(wredm[0][2], wredm[0][3]));
    m1 = fmaxf(fmaxf(wredm[1][0], wredm[1][1]), fmaxf(wredm[1][2], wredm[1][3]));
    m2 = fmaxf(fmaxf(wredm[2][0], wredm[2][1]), fmaxf(wredm[2][2], wredm[2][3]));
    m3 = fmaxf(fmaxf(wredm[3][0], wredm[3][1]), fmaxf(wredm[3][2], wredm[3][3]));

    const float e0 = expf(l0 - m0), e1 = expf(l1 - m1);
    const float e2 = expf(l2 - m2), e3 = expf(l3 - m3);
    float s0 = e0, s1 = e1, s2 = e2, s3 = e3;
    #pragma unroll
    for (int off = 32; off; off >>= 1) {
        s0 += __shfl_xor(s0, off, 64);
        s1 += __shfl_xor(s1, off, 64);
        s2 += __shfl_xor(s2, off, 64);
        s3 += __shfl_xor(s3, off, 64);
    }
    if (lane == 0) {
        wreds[0][wave] = s0; wreds[1][wave] = s1;
        wreds[2][wave] = s2; wreds[3][wave] = s3;
    }
    __syncthreads();
    const float t0 = wreds[0][0] + wreds[0][1] + wreds[0][2] + wreds[0][3];
    const float t1 = wreds[1][0] + wreds[1][1] + wreds[1][2] + wreds[1][3];
    const float t2 = wreds[2][0] + wreds[2][1] + wreds[2][2] + wreds[2][3];
    const float t3 = wreds[3][0] + wreds[3][1] + wreds[3][2] + wreds[3][3];

    scores[(size_t)(b0 + 0) * M + tid] = e0 / t0;
    scores[(size_t)(b0 + 1) * M + tid] = e1 / t1;
    scores[(size_t)(b0 + 2) * M + tid] = e2 / t2;
    scores[(size_t)(b0 + 3) * M + tid] = e3 / t3;
}

// ---------- neuron: mem_new + per-chunk spike counts ----------
// 8-wide m-batches: 8 clustered NT loads, then 8 compute+NT-store.
__global__ __launch_bounds__(256) void neuron_count_kernel(
    const float* __restrict__ x, const float* __restrict__ mem,
    float* __restrict__ mem_new, float* __restrict__ counts,
    int plane4, int nPosBlocks, int mchunk)
{
    const int posb = blockIdx.x % nPosBlocks;
    const int mc   = blockIdx.x / nPosBlocks;
    const int idx  = posb * 256 + threadIdx.x;
    if (idx >= plane4) return;

    const fvec4* x4   = reinterpret_cast<const fvec4*>(x);
    const fvec4* mem4 = reinterpret_cast<const fvec4*>(mem);
    fvec4* out4       = reinterpret_cast<fvec4*>(mem_new);

    const fvec4 xv = x4[idx];
    const int m0 = mc * mchunk;
    float cx = 0.f, cy = 0.f, cz = 0.f, cw = 0.f;

    for (int mm = 0; mm < mchunk; mm += 8) {
        fvec4 mv[8];
        #pragma unroll
        for (int j = 0; j < 8; ++j)
            mv[j] = __builtin_nontemporal_load(
                &mem4[(size_t)(m0 + mm + j) * plane4 + idx]);

        #pragma unroll
        for (int j = 0; j < 8; ++j) {
            const float bm = (float)(m0 + mm + j);
            fvec4 nv;
            nv.x = __fsub_rn(__fadd_rn(__fmul_rn(bm, mv[j].x), xv.x),
                             (mv[j].x - THRESH > 0.f) ? THRESH : 0.f);
            nv.y = __fsub_rn(__fadd_rn(__fmul_rn(bm, mv[j].y), xv.y),
                             (mv[j].y - THRESH > 0.f) ? THRESH : 0.f);
            nv.z = __fsub_rn(__fadd_rn(__fmul_rn(bm, mv[j].z), xv.z),
                             (mv[j].z - THRESH > 0.f) ? THRESH : 0.f);
            nv.w = __fsub_rn(__fadd_rn(__fmul_rn(bm, mv[j].w), xv.w),
                             (mv[j].w - THRESH > 0.f) ? THRESH : 0.f);

            __builtin_nontemporal_store(nv,
                &out4[(size_t)(m0 + mm + j) * plane4 + idx]);

            cx += (nv.x - THRESH > 0.f) ? 1.f : 0.f;
            cy += (nv.y - THRESH > 0.f) ? 1.f : 0.f;
            cz += (nv.z - THRESH > 0.f) ? 1.f : 0.f;
            cw += (nv.w - THRESH > 0.f) ? 1.f : 0.f;
        }
    }
    fvec4 cv; cv.x = cx; cv.y = cy; cv.z = cz; cv.w = cw;
    reinterpret_cast<fvec4*>(counts)[(size_t)mc * plane4 + idx] = cv;
}

// ---------- mix: mixed = scores_flat * sum(counts over chunks) ----------
__global__ __launch_bounds__(256) void mix_kernel(
    const float* __restrict__ scores, const float* __restrict__ counts,
    float* __restrict__ mixed, int plane4, int nchunk)
{
    const int idx = blockIdx.x * 256 + threadIdx.x;
    if (idx >= plane4) return;
    const fvec4* c4 = reinterpret_cast<const fvec4*>(counts);
    fvec4 c = __builtin_nontemporal_load(&c4[idx]);
    for (int j = 1; j < nchunk; ++j) {
        const fvec4 cj = __builtin_nontemporal_load(&c4[(size_t)j * plane4 + idx]);
        c.x += cj.x; c.y += cj.y; c.z += cj.z; c.w += cj.w;
    }
    const fvec4 sc = reinterpret_cast<const fvec4*>(scores)[idx];
    fvec4 mx;
    mx.x = sc.x * c.x; mx.y = sc.y * c.y; mx.z = sc.z * c.z; mx.w = sc.w * c.w;
    reinterpret_cast<fvec4*>(mixed)[idx] = mx;
}

// ---------- fallback kernels (used if ws too small / odd shapes) ----------
__global__ __launch_bounds__(256) void scores_kernel_fb(
    const float* __restrict__ x, const float* __restrict__ W,
    const float* __restrict__ bias, float* __restrict__ scores,
    int D, int M)
{
    const int b = blockIdx.x;
    __shared__ __align__(16) float x_lds[256];
    __shared__ float logits[256];
    __shared__ float wred[4];
    const int tid  = threadIdx.x;
    const int wave = tid >> 6;
    const int lane = tid & 63;
    x_lds[tid] = x[(size_t)b * D + tid];
    __syncthreads();
    const float4* W4 = reinterpret_cast<const float4*>(W);
    const float4  xv = reinterpret_cast<const float4*>(x_lds)[lane];
    for (int i = 0; i < 64; ++i) {
        const int m = wave * 64 + i;
        const float4 wv = W4[(size_t)m * 64 + lane];
        float p = wv.x * xv.x + wv.y * xv.y + wv.z * xv.z + wv.w * xv.w;
        #pragma unroll
        for (int off = 32; off; off >>= 1) p += __shfl_xor(p, off, 64);
        if (lane == 0) logits[m] = p + bias[m];
    }
    __syncthreads();
    float l = logits[tid];
    float mx = l;
    #pragma unroll
    for (int off = 32; off; off >>= 1) mx = fmaxf(mx, __shfl_xor(mx, off, 64));
    if (lane == 0) wred[wave] = mx;
    __syncthreads();
    mx = fmaxf(fmaxf(wred[0], wred[1]), fmaxf(wred[2], wred[3]));
    __syncthreads();
    const float e = expf(l - mx);
    float s = e;
    #pragma unroll
    for (int off = 32; off; off >>= 1) s += __shfl_xor(s, off, 64);
    if (lane == 0) wred[wave] = s;
    __syncthreads();
    const float tot = wred[0] + wred[1] + wred[2] + wred[3];
    scores[(size_t)b * M + tid] = e / tot;
}

__global__ __launch_bounds__(256) void neuron_kernel_fb(
    const float* __restrict__ x, const float* __restrict__ mem,
    const float* __restrict__ scores, float* __restrict__ mixed,
    float* __restrict__ mem_new, int M, int plane4)
{
    const int idx = blockIdx.x * 256 + threadIdx.x;
    if (idx >= plane4) return;
    const float4* x4   = reinterpret_cast<const float4*>(x);
    const float4* mem4 = reinterpret_cast<const float4*>(mem);
    const float4* sc4  = reinterpret_cast<const float4*>(scores);
    float4* out4       = reinterpret_cast<float4*>(mem_new);
    float4* mix4       = reinterpret_cast<float4*>(mixed);
    const float4 xv = x4[idx];
    float cx = 0.f, cy = 0.f, cz = 0.f, cw = 0.f;
    #pragma unroll 4
    for (int m = 0; m < M; ++m) {
        const float bm = (float)m;
        const size_t off = (size_t)m * plane4 + idx;
        const float4 mv = mem4[off];
        float4 nv;
        nv.x = __fsub_rn(__fadd_rn(__fmul_rn(bm, mv.x), xv.x),
                         (mv.x - THRESH > 0.f) ? THRESH : 0.f);
        nv.y = __fsub_rn(__fadd_rn(__fmul_rn(bm, mv.y), xv.y),
                         (mv.y - THRESH > 0.f) ? THRESH : 0.f);
        nv.z = __fsub_rn(__fadd_rn(__fmul_rn(bm, mv.z), xv.z),
                         (mv.z - THRESH > 0.f) ? THRESH : 0.f);
        nv.w = __fsub_rn(__fadd_rn(__fmul_rn(bm, mv.w), xv.w),
                         (mv.w - THRESH > 0.f) ? THRESH : 0.f);
        out4[off] = nv;
        cx += (nv.x - THRESH > 0.f) ? 1.f : 0.f;
        cy += (nv.y - THRESH > 0.f) ? 1.f : 0.f;
        cz += (nv.z - THRESH > 0.f) ? 1.f : 0.f;
        cw += (nv.w - THRESH > 0.f) ? 1.f : 0.f;
    }
    const float4 sc = sc4[idx];
    float4 mx;
    mx.x = sc.x * cx; mx.y = sc.y * cy; mx.z = sc.z * cz; mx.w = sc.w * cw;
    mix4[idx] = mx;
}

extern "C" void kernel_launch(void* const* d_in, const int* in_sizes, int n_in,
                              void* d_out, int out_size, void* d_ws, size_t ws_size,
                              hipStream_t stream) {
    const float* x    = (const float*)d_in[0];
    const float* mem  = (const float*)d_in[1];
    const float* W    = (const float*)d_in[2];
    const float* bias = (const float*)d_in[3];

    const int M = in_sizes[3];             // 256
    const int D = in_sizes[2] / M;         // 256
    const int B = in_sizes[0] / D;         // 1024
    const int plane  = B * D;              // 262144
    const int plane4 = plane / 4;          // 65536

    float* out_mixed  = (float*)d_out;                       // [B*D]
    float* out_mem    = out_mixed + plane;                   // [M*B*D]
    float* out_scores = out_mem + (size_t)M * plane;         // [B*M]

    const int nchunk = 4;
    const int mchunk = M / nchunk;                           // 64
    const size_t wt_bytes    = (size_t)M * D * sizeof(float);        // 256 KB
    const size_t count_bytes = (size_t)nchunk * plane4 * 16;         // 4 MB

    const bool shapes_ok = (B % 4 == 0) && (D == 256) && (M == 256) &&
                           (mchunk % 8 == 0);

    if (shapes_ok && ws_size >= wt_bytes + count_bytes) {
        float* Wt     = (float*)d_ws;
        float* counts = (float*)((char*)d_ws + wt_bytes);

        transpose_kernel<<<(M / 32) * (D / 32), 256, 0, stream>>>(W, Wt, M, D);
        scores_kernel4<<<B / 4, 256, 0, stream>>>(Wt, x, bias, out_scores, D, M);

        const int nPosBlocks = (plane4 + 255) / 256;         // 256
        neuron_count_kernel<<<nPosBlocks * nchunk, 256, 0, stream>>>(
            x, mem, out_mem, counts, plane4, nPosBlocks, mchunk);
        mix_kernel<<<nPosBlocks, 256, 0, stream>>>(
            out_scores, counts, out_mixed, plane4, nchunk);
    } else {
        scores_kernel_fb<<<B, 256, 0, stream>>>(x, W, bias, out_scores, D, M);
        neuron_kernel_fb<<<(plane4 + 255) / 256, 256, 0, stream>>>(
            x, mem, out_scores, out_mixed, out_mem, M, plane4);
    }
}

// Round 5
// 119.053 us; speedup vs baseline: 1.1533x; 1.1533x over previous
//
#include <hip/hip_runtime.h>

#define THRESH 1.0f

typedef float fvec4 __attribute__((ext_vector_type(4)));

// ---------- W transpose: Wt[k][m] = W[m][k] (into d_ws) ----------
__global__ __launch_bounds__(256) void transpose_kernel(
    const float* __restrict__ W, float* __restrict__ Wt, int M, int D)
{
    __shared__ float tile[32][33];
    const int tilesK = D / 32;
    const int bx = blockIdx.x % tilesK;   // k tile
    const int by = blockIdx.x / tilesK;   // m tile
    const int lx = threadIdx.x & 31;
    const int ly = threadIdx.x >> 5;      // 0..7
    #pragma unroll
    for (int j = 0; j < 4; ++j)
        tile[ly + j * 8][lx] = W[(size_t)(by * 32 + ly + j * 8) * D + bx * 32 + lx];
    __syncthreads();
    #pragma unroll
    for (int j = 0; j < 4; ++j)
        Wt[(size_t)(bx * 32 + ly + j * 8) * M + by * 32 + lx] = tile[lx][ly + j * 8];
}

// ---------- fused: role-split blocks ----------
// blocks [0, nScoreBlocks)               : softmax(x@W^T+b), 4 rows per block
// blocks [nScoreBlocks, +nPos*nchunk)    : neuron m-chunk (R3-exact loop)
__global__ __launch_bounds__(256) void fused_kernel(
    const float* __restrict__ x, const float* __restrict__ mem,
    const float* __restrict__ Wt, const float* __restrict__ bias,
    float* __restrict__ mem_new, float* __restrict__ counts,
    float* __restrict__ scores,
    int D, int M, int plane4, int nPosBlocks, int mchunk, int nScoreBlocks)
{
    __shared__ __align__(16) float x_lds[4][256];
    __shared__ float wredm[4][4];   // [row][wave]
    __shared__ float wreds[4][4];

    const int tid = threadIdx.x;

    if ((int)blockIdx.x < nScoreBlocks) {
        // ================= scores role =================
        const int b0   = blockIdx.x * 4;
        const int wave = tid >> 6;
        const int lane = tid & 63;

        #pragma unroll
        for (int r = 0; r < 4; ++r)
            x_lds[r][tid] = x[(size_t)(b0 + r) * D + tid];
        __syncthreads();

        float a0 = 0.f, a1 = 0.f, a2 = 0.f, a3 = 0.f;
        #pragma unroll 2
        for (int k4 = 0; k4 < D / 4; ++k4) {
            const fvec4 x0 = reinterpret_cast<const fvec4*>(x_lds[0])[k4];
            const fvec4 x1 = reinterpret_cast<const fvec4*>(x_lds[1])[k4];
            const fvec4 x2 = reinterpret_cast<const fvec4*>(x_lds[2])[k4];
            const fvec4 x3 = reinterpret_cast<const fvec4*>(x_lds[3])[k4];
            #pragma unroll
            for (int j = 0; j < 4; ++j) {
                const float w = Wt[(size_t)(k4 * 4 + j) * M + tid];
                a0 = fmaf(w, x0[j], a0);
                a1 = fmaf(w, x1[j], a1);
                a2 = fmaf(w, x2[j], a2);
                a3 = fmaf(w, x3[j], a3);
            }
        }
        const float bv = bias[tid];
        float l0 = a0 + bv, l1 = a1 + bv, l2 = a2 + bv, l3 = a3 + bv;

        float m0 = l0, m1 = l1, m2 = l2, m3 = l3;
        #pragma unroll
        for (int off = 32; off; off >>= 1) {
            m0 = fmaxf(m0, __shfl_xor(m0, off, 64));
            m1 = fmaxf(m1, __shfl_xor(m1, off, 64));
            m2 = fmaxf(m2, __shfl_xor(m2, off, 64));
            m3 = fmaxf(m3, __shfl_xor(m3, off, 64));
        }
        if (lane == 0) {
            wredm[0][wave] = m0; wredm[1][wave] = m1;
            wredm[2][wave] = m2; wredm[3][wave] = m3;
        }
        __syncthreads();
        m0 = fmaxf(fmaxf(wredm[0][0], wredm[0][1]), fmaxf(wredm[0][2], wredm[0][3]));
        m1 = fmaxf(fmaxf(wredm[1][0], wredm[1][1]), fmaxf(wredm[1][2], wredm[1][3]));
        m2 = fmaxf(fmaxf(wredm[2][0], wredm[2][1]), fmaxf(wredm[2][2], wredm[2][3]));
        m3 = fmaxf(fmaxf(wredm[3][0], wredm[3][1]), fmaxf(wredm[3][2], wredm[3][3]));

        const float e0 = expf(l0 - m0), e1 = expf(l1 - m1);
        const float e2 = expf(l2 - m2), e3 = expf(l3 - m3);
        float s0 = e0, s1 = e1, s2 = e2, s3 = e3;
        #pragma unroll
        for (int off = 32; off; off >>= 1) {
            s0 += __shfl_xor(s0, off, 64);
            s1 += __shfl_xor(s1, off, 64);
            s2 += __shfl_xor(s2, off, 64);
            s3 += __shfl_xor(s3, off, 64);
        }
        if (lane == 0) {
            wreds[0][wave] = s0; wreds[1][wave] = s1;
            wreds[2][wave] = s2; wreds[3][wave] = s3;
        }
        __syncthreads();
        const float t0 = wreds[0][0] + wreds[0][1] + wreds[0][2] + wreds[0][3];
        const float t1 = wreds[1][0] + wreds[1][1] + wreds[1][2] + wreds[1][3];
        const float t2 = wreds[2][0] + wreds[2][1] + wreds[2][2] + wreds[2][3];
        const float t3 = wreds[3][0] + wreds[3][1] + wreds[3][2] + wreds[3][3];

        scores[(size_t)(b0 + 0) * M + tid] = e0 / t0;
        scores[(size_t)(b0 + 1) * M + tid] = e1 / t1;
        scores[(size_t)(b0 + 2) * M + tid] = e2 / t2;
        scores[(size_t)(b0 + 3) * M + tid] = e3 / t3;
    } else {
        // ================= neuron role (R3-exact inner loop) =================
        const int nb   = blockIdx.x - nScoreBlocks;
        const int posb = nb % nPosBlocks;
        const int mc   = nb / nPosBlocks;
        const int idx  = posb * 256 + tid;
        if (idx >= plane4) return;

        const fvec4* x4   = reinterpret_cast<const fvec4*>(x);
        const fvec4* mem4 = reinterpret_cast<const fvec4*>(mem);
        fvec4* out4       = reinterpret_cast<fvec4*>(mem_new);

        const fvec4 xv = x4[idx];
        const int m0 = mc * mchunk;
        float cx = 0.f, cy = 0.f, cz = 0.f, cw = 0.f;

        #pragma unroll 4
        for (int mm = 0; mm < mchunk; ++mm) {
            const int m = m0 + mm;
            const float bm = (float)m;
            const size_t off = (size_t)m * plane4 + idx;
            const fvec4 mv = __builtin_nontemporal_load(&mem4[off]);

            fvec4 nv;
            nv.x = __fsub_rn(__fadd_rn(__fmul_rn(bm, mv.x), xv.x),
                             (mv.x - THRESH > 0.f) ? THRESH : 0.f);
            nv.y = __fsub_rn(__fadd_rn(__fmul_rn(bm, mv.y), xv.y),
                             (mv.y - THRESH > 0.f) ? THRESH : 0.f);
            nv.z = __fsub_rn(__fadd_rn(__fmul_rn(bm, mv.z), xv.z),
                             (mv.z - THRESH > 0.f) ? THRESH : 0.f);
            nv.w = __fsub_rn(__fadd_rn(__fmul_rn(bm, mv.w), xv.w),
                             (mv.w - THRESH > 0.f) ? THRESH : 0.f);

            __builtin_nontemporal_store(nv, &out4[off]);

            cx += (nv.x - THRESH > 0.f) ? 1.f : 0.f;
            cy += (nv.y - THRESH > 0.f) ? 1.f : 0.f;
            cz += (nv.z - THRESH > 0.f) ? 1.f : 0.f;
            cw += (nv.w - THRESH > 0.f) ? 1.f : 0.f;
        }
        fvec4 cv; cv.x = cx; cv.y = cy; cv.z = cz; cv.w = cw;
        reinterpret_cast<fvec4*>(counts)[(size_t)mc * plane4 + idx] = cv;
    }
}

// ---------- mix: mixed = scores_flat * sum(counts over chunks) ----------
__global__ __launch_bounds__(256) void mix_kernel(
    const float* __restrict__ scores, const float* __restrict__ counts,
    float* __restrict__ mixed, int plane4, int nchunk)
{
    const int idx = blockIdx.x * 256 + threadIdx.x;
    if (idx >= plane4) return;
    const fvec4* c4 = reinterpret_cast<const fvec4*>(counts);
    fvec4 c = __builtin_nontemporal_load(&c4[idx]);
    for (int j = 1; j < nchunk; ++j) {
        const fvec4 cj = __builtin_nontemporal_load(&c4[(size_t)j * plane4 + idx]);
        c.x += cj.x; c.y += cj.y; c.z += cj.z; c.w += cj.w;
    }
    const fvec4 sc = reinterpret_cast<const fvec4*>(scores)[idx];
    fvec4 mx;
    mx.x = sc.x * c.x; mx.y = sc.y * c.y; mx.z = sc.z * c.z; mx.w = sc.w * c.w;
    reinterpret_cast<fvec4*>(mixed)[idx] = mx;
}

// ---------- fallback kernels (used if ws too small / odd shapes) ----------
__global__ __launch_bounds__(256) void scores_kernel_fb(
    const float* __restrict__ x, const float* __restrict__ W,
    const float* __restrict__ bias, float* __restrict__ scores,
    int D, int M)
{
    const int b = blockIdx.x;
    __shared__ __align__(16) float x_lds[256];
    __shared__ float logits[256];
    __shared__ float wred[4];
    const int tid  = threadIdx.x;
    const int wave = tid >> 6;
    const int lane = tid & 63;
    x_lds[tid] = x[(size_t)b * D + tid];
    __syncthreads();
    const float4* W4 = reinterpret_cast<const float4*>(W);
    const float4  xv = reinterpret_cast<const float4*>(x_lds)[lane];
    for (int i = 0; i < 64; ++i) {
        const int m = wave * 64 + i;
        const float4 wv = W4[(size_t)m * 64 + lane];
        float p = wv.x * xv.x + wv.y * xv.y + wv.z * xv.z + wv.w * xv.w;
        #pragma unroll
        for (int off = 32; off; off >>= 1) p += __shfl_xor(p, off, 64);
        if (lane == 0) logits[m] = p + bias[m];
    }
    __syncthreads();
    float l = logits[tid];
    float mx = l;
    #pragma unroll
    for (int off = 32; off; off >>= 1) mx = fmaxf(mx, __shfl_xor(mx, off, 64));
    if (lane == 0) wred[wave] = mx;
    __syncthreads();
    mx = fmaxf(fmaxf(wred[0], wred[1]), fmaxf(wred[2], wred[3]));
    __syncthreads();
    const float e = expf(l - mx);
    float s = e;
    #pragma unroll
    for (int off = 32; off; off >>= 1) s += __shfl_xor(s, off, 64);
    if (lane == 0) wred[wave] = s;
    __syncthreads();
    const float tot = wred[0] + wred[1] + wred[2] + wred[3];
    scores[(size_t)b * M + tid] = e / tot;
}

__global__ __launch_bounds__(256) void neuron_kernel_fb(
    const float* __restrict__ x, const float* __restrict__ mem,
    const float* __restrict__ scores, float* __restrict__ mixed,
    float* __restrict__ mem_new, int M, int plane4)
{
    const int idx = blockIdx.x * 256 + threadIdx.x;
    if (idx >= plane4) return;
    const float4* x4   = reinterpret_cast<const float4*>(x);
    const float4* mem4 = reinterpret_cast<const float4*>(mem);
    const float4* sc4  = reinterpret_cast<const float4*>(scores);
    float4* out4       = reinterpret_cast<float4*>(mem_new);
    float4* mix4       = reinterpret_cast<float4*>(mixed);
    const float4 xv = x4[idx];
    float cx = 0.f, cy = 0.f, cz = 0.f, cw = 0.f;
    #pragma unroll 4
    for (int m = 0; m < M; ++m) {
        const float bm = (float)m;
        const size_t off = (size_t)m * plane4 + idx;
        const float4 mv = mem4[off];
        float4 nv;
        nv.x = __fsub_rn(__fadd_rn(__fmul_rn(bm, mv.x), xv.x),
                         (mv.x - THRESH > 0.f) ? THRESH : 0.f);
        nv.y = __fsub_rn(__fadd_rn(__fmul_rn(bm, mv.y), xv.y),
                         (mv.y - THRESH > 0.f) ? THRESH : 0.f);
        nv.z = __fsub_rn(__fadd_rn(__fmul_rn(bm, mv.z), xv.z),
                         (mv.z - THRESH > 0.f) ? THRESH : 0.f);
        nv.w = __fsub_rn(__fadd_rn(__fmul_rn(bm, mv.w), xv.w),
                         (mv.w - THRESH > 0.f) ? THRESH : 0.f);
        out4[off] = nv;
        cx += (nv.x - THRESH > 0.f) ? 1.f : 0.f;
        cy += (nv.y - THRESH > 0.f) ? 1.f : 0.f;
        cz += (nv.z - THRESH > 0.f) ? 1.f : 0.f;
        cw += (nv.w - THRESH > 0.f) ? 1.f : 0.f;
    }
    const float4 sc = sc4[idx];
    float4 mx;
    mx.x = sc.x * cx; mx.y = sc.y * cy; mx.z = sc.z * cz; mx.w = sc.w * cw;
    mix4[idx] = mx;
}

extern "C" void kernel_launch(void* const* d_in, const int* in_sizes, int n_in,
                              void* d_out, int out_size, void* d_ws, size_t ws_size,
                              hipStream_t stream) {
    const float* x    = (const float*)d_in[0];
    const float* mem  = (const float*)d_in[1];
    const float* W    = (const float*)d_in[2];
    const float* bias = (const float*)d_in[3];

    const int M = in_sizes[3];             // 256
    const int D = in_sizes[2] / M;         // 256
    const int B = in_sizes[0] / D;         // 1024
    const int plane  = B * D;              // 262144
    const int plane4 = plane / 4;          // 65536

    float* out_mixed  = (float*)d_out;                       // [B*D]
    float* out_mem    = out_mixed + plane;                   // [M*B*D]
    float* out_scores = out_mem + (size_t)M * plane;         // [B*M]

    const int nchunk = 4;
    const int mchunk = M / nchunk;                           // 64
    const size_t wt_bytes    = (size_t)M * D * sizeof(float);        // 256 KB
    const size_t count_bytes = (size_t)nchunk * plane4 * 16;         // 4 MB

    const bool shapes_ok = (B % 4 == 0) && (D == 256) && (M == 256) &&
                           (mchunk % 4 == 0);

    if (shapes_ok && ws_size >= wt_bytes + count_bytes) {
        float* Wt     = (float*)d_ws;
        float* counts = (float*)((char*)d_ws + wt_bytes);

        transpose_kernel<<<(M / 32) * (D / 32), 256, 0, stream>>>(W, Wt, M, D);

        const int nPosBlocks   = (plane4 + 255) / 256;       // 256
        const int nScoreBlocks = B / 4;                      // 256
        const int grid = nScoreBlocks + nPosBlocks * nchunk; // 1280
        fused_kernel<<<grid, 256, 0, stream>>>(
            x, mem, Wt, bias, out_mem, counts, out_scores,
            D, M, plane4, nPosBlocks, mchunk, nScoreBlocks);

        mix_kernel<<<nPosBlocks, 256, 0, stream>>>(
            out_scores, counts, out_mixed, plane4, nchunk);
    } else {
        scores_kernel_fb<<<B, 256, 0, stream>>>(x, W, bias, out_scores, D, M);
        neuron_kernel_fb<<<(plane4 + 255) / 256, 256, 0, stream>>>(
            x, mem, out_scores, out_mixed, out_mem, M, plane4);
    }
}

// Round 6
// 111.686 us; speedup vs baseline: 1.2294x; 1.0660x over previous
//
#include <hip/hip_runtime.h>

#define THRESH 1.0f

typedef float fvec4 __attribute__((ext_vector_type(4)));

// ---------- W transpose: Wt[k][m] = W[m][k] (into d_ws) ----------
__global__ __launch_bounds__(256) void transpose_kernel(
    const float* __restrict__ W, float* __restrict__ Wt, int M, int D)
{
    __shared__ float tile[32][33];
    const int tilesK = D / 32;
    const int bx = blockIdx.x % tilesK;   // k tile
    const int by = blockIdx.x / tilesK;   // m tile
    const int lx = threadIdx.x & 31;
    const int ly = threadIdx.x >> 5;      // 0..7
    #pragma unroll
    for (int j = 0; j < 4; ++j)
        tile[ly + j * 8][lx] = W[(size_t)(by * 32 + ly + j * 8) * D + bx * 32 + lx];
    __syncthreads();
    #pragma unroll
    for (int j = 0; j < 4; ++j)
        Wt[(size_t)(bx * 32 + ly + j * 8) * M + by * 32 + lx] = tile[lx][ly + j * 8];
}

// ---------- mega kernel: one block per batch row ----------
// Wave 0: softmax(x[b]@W^T+b) prologue (Wt from L2, ~3us) then its m-segment.
// Waves 1-3: straight into the neuron HBM stream (m-segments 64..255).
// Epilogue: LDS count-reduce + mixed = scores_row * count. No counts buffer,
// no mix kernel, no separate scores dispatch.
__global__ __launch_bounds__(256) void mega_kernel(
    const float* __restrict__ x, const float* __restrict__ mem,
    const float* __restrict__ Wt, const float* __restrict__ bias,
    float* __restrict__ mem_new, float* __restrict__ scores,
    float* __restrict__ mixed, int plane4)
{
    const int b    = blockIdx.x;
    const int tid  = threadIdx.x;
    const int wave = tid >> 6;
    const int lane = tid & 63;

    __shared__ __align__(16) float x_lds[256];
    __shared__ fvec4 sc_lds[64];
    __shared__ fvec4 cnt_lds[4][64];

    x_lds[tid] = x[(size_t)b * 256 + tid];
    __syncthreads();

    if (wave == 0) {
        // ---- scores prologue: lane owns logits m = lane*4..lane*4+3 ----
        const fvec4* Wt4 = reinterpret_cast<const fvec4*>(Wt);
        fvec4 acc = {0.f, 0.f, 0.f, 0.f};
        #pragma unroll 4
        for (int k = 0; k < 256; ++k) {
            const fvec4 w = Wt4[(size_t)k * 64 + lane];   // coalesced, L2-hot
            const float xk = x_lds[k];                    // LDS broadcast
            acc.x = fmaf(w.x, xk, acc.x);
            acc.y = fmaf(w.y, xk, acc.y);
            acc.z = fmaf(w.z, xk, acc.z);
            acc.w = fmaf(w.w, xk, acc.w);
        }
        const fvec4 bv = reinterpret_cast<const fvec4*>(bias)[lane];
        fvec4 lg;
        lg.x = acc.x + bv.x; lg.y = acc.y + bv.y;
        lg.z = acc.z + bv.z; lg.w = acc.w + bv.w;

        float mx = fmaxf(fmaxf(lg.x, lg.y), fmaxf(lg.z, lg.w));
        #pragma unroll
        for (int off = 32; off; off >>= 1) mx = fmaxf(mx, __shfl_xor(mx, off, 64));

        fvec4 e;
        e.x = expf(lg.x - mx); e.y = expf(lg.y - mx);
        e.z = expf(lg.z - mx); e.w = expf(lg.w - mx);
        float s = (e.x + e.y) + (e.z + e.w);
        #pragma unroll
        for (int off = 32; off; off >>= 1) s += __shfl_xor(s, off, 64);

        fvec4 sc;
        sc.x = e.x / s; sc.y = e.y / s; sc.z = e.z / s; sc.w = e.w / s;
        sc_lds[lane] = sc;
        reinterpret_cast<fvec4*>(scores)[(size_t)b * 64 + lane] = sc;
    }

    // ---- neuron: all waves, m-segment = [wave*64, wave*64+64) ----
    const int idx4 = b * 64 + lane;                      // float4 position
    const fvec4 xv = reinterpret_cast<const fvec4*>(x_lds)[lane];
    const fvec4* mem4 = reinterpret_cast<const fvec4*>(mem);
    fvec4* out4       = reinterpret_cast<fvec4*>(mem_new);

    float cx = 0.f, cy = 0.f, cz = 0.f, cw = 0.f;
    const int m0 = wave * 64;

    #pragma unroll 4
    for (int j = 0; j < 64; ++j) {
        const int m = m0 + j;
        const float bm = (float)m;
        const size_t off = (size_t)m * plane4 + idx4;
        const fvec4 mv = __builtin_nontemporal_load(&mem4[off]);

        fvec4 nv;
        nv.x = __fsub_rn(__fadd_rn(__fmul_rn(bm, mv.x), xv.x),
                         (mv.x - THRESH > 0.f) ? THRESH : 0.f);
        nv.y = __fsub_rn(__fadd_rn(__fmul_rn(bm, mv.y), xv.y),
                         (mv.y - THRESH > 0.f) ? THRESH : 0.f);
        nv.z = __fsub_rn(__fadd_rn(__fmul_rn(bm, mv.z), xv.z),
                         (mv.z - THRESH > 0.f) ? THRESH : 0.f);
        nv.w = __fsub_rn(__fadd_rn(__fmul_rn(bm, mv.w), xv.w),
                         (mv.w - THRESH > 0.f) ? THRESH : 0.f);

        __builtin_nontemporal_store(nv, &out4[off]);

        cx += (nv.x - THRESH > 0.f) ? 1.f : 0.f;
        cy += (nv.y - THRESH > 0.f) ? 1.f : 0.f;
        cz += (nv.z - THRESH > 0.f) ? 1.f : 0.f;
        cw += (nv.w - THRESH > 0.f) ? 1.f : 0.f;
    }
    fvec4 cv; cv.x = cx; cv.y = cy; cv.z = cz; cv.w = cw;
    cnt_lds[wave][lane] = cv;
    __syncthreads();

    // ---- epilogue: mixed[b, :] = scores[b, :] * counts ----
    if (wave == 0) {
        const fvec4 c0 = cnt_lds[0][lane];
        const fvec4 c1 = cnt_lds[1][lane];
        const fvec4 c2 = cnt_lds[2][lane];
        const fvec4 c3 = cnt_lds[3][lane];
        fvec4 c;
        c.x = (c0.x + c1.x) + (c2.x + c3.x);
        c.y = (c0.y + c1.y) + (c2.y + c3.y);
        c.z = (c0.z + c1.z) + (c2.z + c3.z);
        c.w = (c0.w + c1.w) + (c2.w + c3.w);
        const fvec4 sc = sc_lds[lane];
        fvec4 r;
        r.x = sc.x * c.x; r.y = sc.y * c.y;
        r.z = sc.z * c.z; r.w = sc.w * c.w;
        reinterpret_cast<fvec4*>(mixed)[(size_t)idx4] = r;
    }
}

// ---------- fallback kernels (used if ws too small / odd shapes) ----------
__global__ __launch_bounds__(256) void scores_kernel_fb(
    const float* __restrict__ x, const float* __restrict__ W,
    const float* __restrict__ bias, float* __restrict__ scores,
    int D, int M)
{
    const int b = blockIdx.x;
    __shared__ __align__(16) float x_lds[256];
    __shared__ float logits[256];
    __shared__ float wred[4];
    const int tid  = threadIdx.x;
    const int wave = tid >> 6;
    const int lane = tid & 63;
    x_lds[tid] = x[(size_t)b * D + tid];
    __syncthreads();
    const float4* W4 = reinterpret_cast<const float4*>(W);
    const float4  xv = reinterpret_cast<const float4*>(x_lds)[lane];
    for (int i = 0; i < 64; ++i) {
        const int m = wave * 64 + i;
        const float4 wv = W4[(size_t)m * 64 + lane];
        float p = wv.x * xv.x + wv.y * xv.y + wv.z * xv.z + wv.w * xv.w;
        #pragma unroll
        for (int off = 32; off; off >>= 1) p += __shfl_xor(p, off, 64);
        if (lane == 0) logits[m] = p + bias[m];
    }
    __syncthreads();
    float l = logits[tid];
    float mx = l;
    #pragma unroll
    for (int off = 32; off; off >>= 1) mx = fmaxf(mx, __shfl_xor(mx, off, 64));
    if (lane == 0) wred[wave] = mx;
    __syncthreads();
    mx = fmaxf(fmaxf(wred[0], wred[1]), fmaxf(wred[2], wred[3]));
    __syncthreads();
    const float e = expf(l - mx);
    float s = e;
    #pragma unroll
    for (int off = 32; off; off >>= 1) s += __shfl_xor(s, off, 64);
    if (lane == 0) wred[wave] = s;
    __syncthreads();
    const float tot = wred[0] + wred[1] + wred[2] + wred[3];
    scores[(size_t)b * M + tid] = e / tot;
}

__global__ __launch_bounds__(256) void neuron_kernel_fb(
    const float* __restrict__ x, const float* __restrict__ mem,
    const float* __restrict__ scores, float* __restrict__ mixed,
    float* __restrict__ mem_new, int M, int plane4)
{
    const int idx = blockIdx.x * 256 + threadIdx.x;
    if (idx >= plane4) return;
    const float4* x4   = reinterpret_cast<const float4*>(x);
    const float4* mem4 = reinterpret_cast<const float4*>(mem);
    const float4* sc4  = reinterpret_cast<const float4*>(scores);
    float4* out4       = reinterpret_cast<float4*>(mem_new);
    float4* mix4       = reinterpret_cast<float4*>(mixed);
    const float4 xv = x4[idx];
    float cx = 0.f, cy = 0.f, cz = 0.f, cw = 0.f;
    #pragma unroll 4
    for (int m = 0; m < M; ++m) {
        const float bm = (float)m;
        const size_t off = (size_t)m * plane4 + idx;
        const float4 mv = mem4[off];
        float4 nv;
        nv.x = __fsub_rn(__fadd_rn(__fmul_rn(bm, mv.x), xv.x),
                         (mv.x - THRESH > 0.f) ? THRESH : 0.f);
        nv.y = __fsub_rn(__fadd_rn(__fmul_rn(bm, mv.y), xv.y),
                         (mv.y - THRESH > 0.f) ? THRESH : 0.f);
        nv.z = __fsub_rn(__fadd_rn(__fmul_rn(bm, mv.z), xv.z),
                         (mv.z - THRESH > 0.f) ? THRESH : 0.f);
        nv.w = __fsub_rn(__fadd_rn(__fmul_rn(bm, mv.w), xv.w),
                         (mv.w - THRESH > 0.f) ? THRESH : 0.f);
        out4[off] = nv;
        cx += (nv.x - THRESH > 0.f) ? 1.f : 0.f;
        cy += (nv.y - THRESH > 0.f) ? 1.f : 0.f;
        cz += (nv.z - THRESH > 0.f) ? 1.f : 0.f;
        cw += (nv.w - THRESH > 0.f) ? 1.f : 0.f;
    }
    const float4 sc = sc4[idx];
    float4 mx;
    mx.x = sc.x * cx; mx.y = sc.y * cy; mx.z = sc.z * cz; mx.w = sc.w * cw;
    mix4[idx] = mx;
}

extern "C" void kernel_launch(void* const* d_in, const int* in_sizes, int n_in,
                              void* d_out, int out_size, void* d_ws, size_t ws_size,
                              hipStream_t stream) {
    const float* x    = (const float*)d_in[0];
    const float* mem  = (const float*)d_in[1];
    const float* W    = (const float*)d_in[2];
    const float* bias = (const float*)d_in[3];

    const int M = in_sizes[3];             // 256
    const int D = in_sizes[2] / M;         // 256
    const int B = in_sizes[0] / D;         // 1024
    const int plane  = B * D;              // 262144
    const int plane4 = plane / 4;          // 65536

    float* out_mixed  = (float*)d_out;                       // [B*D]
    float* out_mem    = out_mixed + plane;                   // [M*B*D]
    float* out_scores = out_mem + (size_t)M * plane;         // [B*M]

    const size_t wt_bytes = (size_t)M * D * sizeof(float);   // 256 KB

    const bool shapes_ok = (D == 256) && (M == 256);

    if (shapes_ok && ws_size >= wt_bytes) {
        float* Wt = (float*)d_ws;
        transpose_kernel<<<(M / 32) * (D / 32), 256, 0, stream>>>(W, Wt, M, D);
        mega_kernel<<<B, 256, 0, stream>>>(
            x, mem, Wt, bias, out_mem, out_scores, out_mixed, plane4);
    } else {
        scores_kernel_fb<<<B, 256, 0, stream>>>(x, W, bias, out_scores, D, M);
        neuron_kernel_fb<<<(plane4 + 255) / 256, 256, 0, stream>>>(
            x, mem, out_scores, out_mixed, out_mem, M, plane4);
    }
}

// Round 7
// 106.668 us; speedup vs baseline: 1.2872x; 1.0470x over previous
//
#include <hip/hip_runtime.h>

#define THRESH 1.0f

typedef float fvec4 __attribute__((ext_vector_type(4)));

__device__ __forceinline__ float rl(float v, int l) {
    return __int_as_float(__builtin_amdgcn_readlane(__float_as_int(v), l));
}

// ---------- W transpose: Wt[k][m] = W[m][k] (into d_ws) ----------
__global__ __launch_bounds__(256) void transpose_kernel(
    const float* __restrict__ W, float* __restrict__ Wt, int M, int D)
{
    __shared__ float tile[32][33];
    const int tilesK = D / 32;
    const int bx = blockIdx.x % tilesK;   // k tile
    const int by = blockIdx.x / tilesK;   // m tile
    const int lx = threadIdx.x & 31;
    const int ly = threadIdx.x >> 5;      // 0..7
    #pragma unroll
    for (int j = 0; j < 4; ++j)
        tile[ly + j * 8][lx] = W[(size_t)(by * 32 + ly + j * 8) * D + bx * 32 + lx];
    __syncthreads();
    #pragma unroll
    for (int j = 0; j < 4; ++j)
        Wt[(size_t)(bx * 32 + ly + j * 8) * M + by * 32 + lx] = tile[lx][ly + j * 8];
}

// ---------- row-pair kernel: block = rows (b0, b0+1) ----------
// Prologue (all 4 waves): thread tid owns logit m=tid for both rows.
//   Wt read ONCE per block (256 KB); x broadcast via v_readlane (no LDS pipe).
// Neuron: thread = (h=tid>>7, p=tid&127): position p of the 2-row panel,
//   m in [128h, 128h+128), counts in registers. One LDS half-combine.
// Epilogue (h==0): mixed = scores * (cnt0 + cnt1). Counts are exact ints.
__global__ __launch_bounds__(256) void rowpair_kernel(
    const float* __restrict__ x, const float* __restrict__ mem,
    const float* __restrict__ Wt, const float* __restrict__ bias,
    float* __restrict__ mem_new, float* __restrict__ scores,
    float* __restrict__ mixed, int plane4)
{
    const int b0   = blockIdx.x * 2;
    const int tid  = threadIdx.x;
    const int wave = tid >> 6;
    const int lane = tid & 63;

    __shared__ __align__(16) float sc_lds[2][256];
    __shared__ fvec4 cnt_lds[2][128];
    __shared__ float wredm[2][4];
    __shared__ float wreds[2][4];

    // ---- prologue: each wave holds both x rows in registers ----
    const fvec4 xq0 = reinterpret_cast<const fvec4*>(x)[(size_t)b0 * 64 + lane];
    const fvec4 xq1 = reinterpret_cast<const fvec4*>(x)[(size_t)(b0 + 1) * 64 + lane];

    float a0 = 0.f, a1 = 0.f;
    #pragma unroll 4
    for (int j = 0; j < 64; ++j) {
        const float w0 = Wt[(size_t)(4 * j + 0) * 256 + tid];
        const float w1 = Wt[(size_t)(4 * j + 1) * 256 + tid];
        const float w2 = Wt[(size_t)(4 * j + 2) * 256 + tid];
        const float w3 = Wt[(size_t)(4 * j + 3) * 256 + tid];
        a0 = fmaf(w0, rl(xq0.x, j), a0);
        a0 = fmaf(w1, rl(xq0.y, j), a0);
        a0 = fmaf(w2, rl(xq0.z, j), a0);
        a0 = fmaf(w3, rl(xq0.w, j), a0);
        a1 = fmaf(w0, rl(xq1.x, j), a1);
        a1 = fmaf(w1, rl(xq1.y, j), a1);
        a1 = fmaf(w2, rl(xq1.z, j), a1);
        a1 = fmaf(w3, rl(xq1.w, j), a1);
    }
    const float bv = bias[tid];
    const float l0 = a0 + bv, l1 = a1 + bv;

    float m0 = l0, m1 = l1;
    #pragma unroll
    for (int off = 32; off; off >>= 1) {
        m0 = fmaxf(m0, __shfl_xor(m0, off, 64));
        m1 = fmaxf(m1, __shfl_xor(m1, off, 64));
    }
    if (lane == 0) { wredm[0][wave] = m0; wredm[1][wave] = m1; }
    __syncthreads();
    m0 = fmaxf(fmaxf(wredm[0][0], wredm[0][1]), fmaxf(wredm[0][2], wredm[0][3]));
    m1 = fmaxf(fmaxf(wredm[1][0], wredm[1][1]), fmaxf(wredm[1][2], wredm[1][3]));

    const float e0 = expf(l0 - m0), e1 = expf(l1 - m1);
    float s0 = e0, s1 = e1;
    #pragma unroll
    for (int off = 32; off; off >>= 1) {
        s0 += __shfl_xor(s0, off, 64);
        s1 += __shfl_xor(s1, off, 64);
    }
    if (lane == 0) { wreds[0][wave] = s0; wreds[1][wave] = s1; }
    __syncthreads();
    const float t0 = wreds[0][0] + wreds[0][1] + wreds[0][2] + wreds[0][3];
    const float t1 = wreds[1][0] + wreds[1][1] + wreds[1][2] + wreds[1][3];

    const float sc0 = e0 / t0, sc1 = e1 / t1;
    sc_lds[0][tid] = sc0;
    sc_lds[1][tid] = sc1;
    scores[(size_t)b0 * 256 + tid]       = sc0;
    scores[(size_t)(b0 + 1) * 256 + tid] = sc1;

    // ---- neuron stream: full-m count in registers, half per thread ----
    const int h = tid >> 7;               // m-half
    const int p = tid & 127;              // position in 2-row panel
    const int pos4 = b0 * 64 + p;         // float4 index in [B,D] plane
    const fvec4 xv = reinterpret_cast<const fvec4*>(x)[pos4];   // L2 hit

    const fvec4* mem4 = reinterpret_cast<const fvec4*>(mem);
    fvec4* out4       = reinterpret_cast<fvec4*>(mem_new);

    float cx = 0.f, cy = 0.f, cz = 0.f, cw = 0.f;
    const int mstart = h * 128;

    #pragma unroll 8
    for (int mm = 0; mm < 128; ++mm) {
        const int m = mstart + mm;
        const float bm = (float)m;
        const size_t off = (size_t)m * plane4 + pos4;
        const fvec4 mv = __builtin_nontemporal_load(&mem4[off]);

        fvec4 nv;
        nv.x = __fsub_rn(__fadd_rn(__fmul_rn(bm, mv.x), xv.x),
                         (mv.x - THRESH > 0.f) ? THRESH : 0.f);
        nv.y = __fsub_rn(__fadd_rn(__fmul_rn(bm, mv.y), xv.y),
                         (mv.y - THRESH > 0.f) ? THRESH : 0.f);
        nv.z = __fsub_rn(__fadd_rn(__fmul_rn(bm, mv.z), xv.z),
                         (mv.z - THRESH > 0.f) ? THRESH : 0.f);
        nv.w = __fsub_rn(__fadd_rn(__fmul_rn(bm, mv.w), xv.w),
                         (mv.w - THRESH > 0.f) ? THRESH : 0.f);

        __builtin_nontemporal_store(nv, &out4[off]);

        cx += (nv.x - THRESH > 0.f) ? 1.f : 0.f;
        cy += (nv.y - THRESH > 0.f) ? 1.f : 0.f;
        cz += (nv.z - THRESH > 0.f) ? 1.f : 0.f;
        cw += (nv.w - THRESH > 0.f) ? 1.f : 0.f;
    }
    fvec4 cv; cv.x = cx; cv.y = cy; cv.z = cz; cv.w = cw;
    cnt_lds[h][p] = cv;
    __syncthreads();

    // ---- epilogue: mixed[pos] = scores_flat[pos] * total count ----
    if (h == 0) {
        const fvec4 cA = cnt_lds[0][p];
        const fvec4 cB = cnt_lds[1][p];
        const fvec4 sc = reinterpret_cast<const fvec4*>(sc_lds[p >> 6])[p & 63];
        fvec4 r;
        r.x = sc.x * (cA.x + cB.x);
        r.y = sc.y * (cA.y + cB.y);
        r.z = sc.z * (cA.z + cB.z);
        r.w = sc.w * (cA.w + cB.w);
        reinterpret_cast<fvec4*>(mixed)[pos4] = r;
    }
}

// ---------- fallback kernels (used if ws too small / odd shapes) ----------
__global__ __launch_bounds__(256) void scores_kernel_fb(
    const float* __restrict__ x, const float* __restrict__ W,
    const float* __restrict__ bias, float* __restrict__ scores,
    int D, int M)
{
    const int b = blockIdx.x;
    __shared__ __align__(16) float x_lds[256];
    __shared__ float logits[256];
    __shared__ float wred[4];
    const int tid  = threadIdx.x;
    const int wave = tid >> 6;
    const int lane = tid & 63;
    x_lds[tid] = x[(size_t)b * D + tid];
    __syncthreads();
    const float4* W4 = reinterpret_cast<const float4*>(W);
    const float4  xv = reinterpret_cast<const float4*>(x_lds)[lane];
    for (int i = 0; i < 64; ++i) {
        const int m = wave * 64 + i;
        const float4 wv = W4[(size_t)m * 64 + lane];
        float p = wv.x * xv.x + wv.y * xv.y + wv.z * xv.z + wv.w * xv.w;
        #pragma unroll
        for (int off = 32; off; off >>= 1) p += __shfl_xor(p, off, 64);
        if (lane == 0) logits[m] = p + bias[m];
    }
    __syncthreads();
    float l = logits[tid];
    float mx = l;
    #pragma unroll
    for (int off = 32; off; off >>= 1) mx = fmaxf(mx, __shfl_xor(mx, off, 64));
    if (lane == 0) wred[wave] = mx;
    __syncthreads();
    mx = fmaxf(fmaxf(wred[0], wred[1]), fmaxf(wred[2], wred[3]));
    __syncthreads();
    const float e = expf(l - mx);
    float s = e;
    #pragma unroll
    for (int off = 32; off; off >>= 1) s += __shfl_xor(s, off, 64);
    if (lane == 0) wred[wave] = s;
    __syncthreads();
    const float tot = wred[0] + wred[1] + wred[2] + wred[3];
    scores[(size_t)b * M + tid] = e / tot;
}

__global__ __launch_bounds__(256) void neuron_kernel_fb(
    const float* __restrict__ x, const float* __restrict__ mem,
    const float* __restrict__ scores, float* __restrict__ mixed,
    float* __restrict__ mem_new, int M, int plane4)
{
    const int idx = blockIdx.x * 256 + threadIdx.x;
    if (idx >= plane4) return;
    const float4* x4   = reinterpret_cast<const float4*>(x);
    const float4* mem4 = reinterpret_cast<const float4*>(mem);
    const float4* sc4  = reinterpret_cast<const float4*>(scores);
    float4* out4       = reinterpret_cast<float4*>(mem_new);
    float4* mix4       = reinterpret_cast<float4*>(mixed);
    const float4 xv = x4[idx];
    float cx = 0.f, cy = 0.f, cz = 0.f, cw = 0.f;
    #pragma unroll 4
    for (int m = 0; m < M; ++m) {
        const float bm = (float)m;
        const size_t off = (size_t)m * plane4 + idx;
        const float4 mv = mem4[off];
        float4 nv;
        nv.x = __fsub_rn(__fadd_rn(__fmul_rn(bm, mv.x), xv.x),
                         (mv.x - THRESH > 0.f) ? THRESH : 0.f);
        nv.y = __fsub_rn(__fadd_rn(__fmul_rn(bm, mv.y), xv.y),
                         (mv.y - THRESH > 0.f) ? THRESH : 0.f);
        nv.z = __fsub_rn(__fadd_rn(__fmul_rn(bm, mv.z), xv.z),
                         (mv.z - THRESH > 0.f) ? THRESH : 0.f);
        nv.w = __fsub_rn(__fadd_rn(__fmul_rn(bm, mv.w), xv.w),
                         (mv.w - THRESH > 0.f) ? THRESH : 0.f);
        out4[off] = nv;
        cx += (nv.x - THRESH > 0.f) ? 1.f : 0.f;
        cy += (nv.y - THRESH > 0.f) ? 1.f : 0.f;
        cz += (nv.z - THRESH > 0.f) ? 1.f : 0.f;
        cw += (nv.w - THRESH > 0.f) ? 1.f : 0.f;
    }
    const float4 sc = sc4[idx];
    float4 mx;
    mx.x = sc.x * cx; mx.y = sc.y * cy; mx.z = sc.z * cz; mx.w = sc.w * cw;
    mix4[idx] = mx;
}

extern "C" void kernel_launch(void* const* d_in, const int* in_sizes, int n_in,
                              void* d_out, int out_size, void* d_ws, size_t ws_size,
                              hipStream_t stream) {
    const float* x    = (const float*)d_in[0];
    const float* mem  = (const float*)d_in[1];
    const float* W    = (const float*)d_in[2];
    const float* bias = (const float*)d_in[3];

    const int M = in_sizes[3];             // 256
    const int D = in_sizes[2] / M;         // 256
    const int B = in_sizes[0] / D;         // 1024
    const int plane  = B * D;              // 262144
    const int plane4 = plane / 4;          // 65536

    float* out_mixed  = (float*)d_out;                       // [B*D]
    float* out_mem    = out_mixed + plane;                   // [M*B*D]
    float* out_scores = out_mem + (size_t)M * plane;         // [B*M]

    const size_t wt_bytes = (size_t)M * D * sizeof(float);   // 256 KB

    const bool shapes_ok = (D == 256) && (M == 256) && (B % 2 == 0);

    if (shapes_ok && ws_size >= wt_bytes) {
        float* Wt = (float*)d_ws;
        transpose_kernel<<<(M / 32) * (D / 32), 256, 0, stream>>>(W, Wt, M, D);
        rowpair_kernel<<<B / 2, 256, 0, stream>>>(
            x, mem, Wt, bias, out_mem, out_scores, out_mixed, plane4);
    } else {
        scores_kernel_fb<<<B, 256, 0, stream>>>(x, W, bias, out_scores, D, M);
        neuron_kernel_fb<<<(plane + 255) / 256 / 4, 256, 0, stream>>>(
            x, mem, out_scores, out_mixed, out_mem, M, plane4);
    }
}